// Round 8
// baseline (75.953 us; speedup 1.0000x reference)
//
#include <hip/hip_runtime.h>
#include <hip/hip_bf16.h>

// Fused (3 kernels): qkv = x @ w_qkv^T (fp32 in, bf16 out, V emitted transposed) ;
// blockmasked 16-head MFMA flash attention (kv-split x2, no-max softmax) ;
// out = attn @ w_fc^T (fp32 out).  L=1152, D=1024, NH=16, DH=64, N_PC=1024.
// GEMMs reg-stage fp32 global loads -> in-register bf16 cvt -> swizzled ds_write,
// one barrier per K-tile, loads one compute-phase deep (T14 issue-early).

typedef short bf16x8 __attribute__((ext_vector_type(8)));
typedef float f32x4 __attribute__((ext_vector_type(4)));

#define L_SEQ   1152
#define NPC     1024
#define DMODEL  1024
#define TD      3072
#define NHEADS  16
#define DHEAD   64

__device__ __forceinline__ void gld_lds16(const void* g, void* l) {
  __builtin_amdgcn_global_load_lds((const __attribute__((address_space(1))) void*)g,
                                   (__attribute__((address_space(3))) void*)l,
                                   16, 0, 0);
}

template <int N>
__device__ __forceinline__ void s_wait_vmcnt() {
  if constexpr (N == 0)      asm volatile("s_waitcnt vmcnt(0)" ::: "memory");
  else if constexpr (N == 8) asm volatile("s_waitcnt vmcnt(8)" ::: "memory");
  else static_assert(N == 0, "add vmcnt case");
}

__device__ __forceinline__ short f2b(float f) {
  __hip_bfloat16 h = __float2bfloat16(f);
  short s;
  __builtin_memcpy(&s, &h, 2);
  return s;
}

// ---------------- GEMM1: qkv[l,e](bf16) = x[l,d]f32 * w_qkv[e,d]^T f32 ----------
// 128x128 tile, BK=64, 4 waves (2x2, wave-tile 64x64). Reg-staged fp32 -> bf16.
// n-tiles >=16 (V region) written transposed to vT[e][l].
__global__ __launch_bounds__(256) void gemm1_rs(
    const float* __restrict__ A, const float* __restrict__ B,
    __hip_bfloat16* __restrict__ C, __hip_bfloat16* __restrict__ vT) {
  constexpr int K = 1024, NK = 16, N = TD;
  __shared__ __align__(16) char smem[2 * 128 * 64 * 2 * 2];  // As[2]+Bs[2], 64 KB
  __hip_bfloat16* As = (__hip_bfloat16*)smem;
  __hip_bfloat16* Bs = (__hip_bfloat16*)(smem + 2 * 128 * 64 * 2);

  const int tid = threadIdx.x, lane = tid & 63, w = tid >> 6;
  const int wm = w >> 1, wn = w & 1, l15 = lane & 15, lg = lane >> 4;
  // XCD swizzle (216 = 8*27), column-chunked: n = wgid/9 fast-varying per chunk
  const int wgid = ((int)blockIdx.x & 7) * 27 + ((int)blockIdx.x >> 3);
  const int n0 = (wgid / 9) * 128, m0 = (wgid % 9) * 128;

  f32x4 acc[4][4] = {};
  float4 ra[4][2], rb[4][2];   // staged fp32: 4 chunks x 8 f32 per matrix

  auto issue = [&](int kt) {
#pragma unroll
    for (int i = 0; i < 4; ++i) {
      int c = i * 256 + tid;
      int r = c >> 3, cs = c & 7;
      const float* pa = A + (size_t)(m0 + r) * K + kt + cs * 8;
      ra[i][0] = *(const float4*)pa;
      ra[i][1] = *(const float4*)(pa + 4);
      const float* pb = B + (size_t)(n0 + r) * K + kt + cs * 8;
      rb[i][0] = *(const float4*)pb;
      rb[i][1] = *(const float4*)(pb + 4);
    }
  };
  auto writebuf = [&](int b) {
#pragma unroll
    for (int i = 0; i < 4; ++i) {
      int c = i * 256 + tid;
      int r = c >> 3, cs = c & 7;
      bf16x8 va, vb;
      va[0] = f2b(ra[i][0].x); va[1] = f2b(ra[i][0].y);
      va[2] = f2b(ra[i][0].z); va[3] = f2b(ra[i][0].w);
      va[4] = f2b(ra[i][1].x); va[5] = f2b(ra[i][1].y);
      va[6] = f2b(ra[i][1].z); va[7] = f2b(ra[i][1].w);
      vb[0] = f2b(rb[i][0].x); vb[1] = f2b(rb[i][0].y);
      vb[2] = f2b(rb[i][0].z); vb[3] = f2b(rb[i][0].w);
      vb[4] = f2b(rb[i][1].x); vb[5] = f2b(rb[i][1].y);
      vb[6] = f2b(rb[i][1].z); vb[7] = f2b(rb[i][1].w);
      int slot = (r * 8 + (cs ^ (r & 7))) * 8;     // XOR-swizzled LDS slot
      *(bf16x8*)&As[b * (128 * 64) + slot] = va;
      *(bf16x8*)&Bs[b * (128 * 64) + slot] = vb;
    }
  };
  auto compute = [&](int b) {
#pragma unroll
    for (int kk = 0; kk < 2; ++kk) {
      bf16x8 af[4], bfr[4];
#pragma unroll
      for (int i = 0; i < 4; ++i) {
        int r = wm * 64 + i * 16 + l15;
        af[i] = *(const bf16x8*)&As[b * (128 * 64) + (r * 8 + (((kk << 2) + lg) ^ (r & 7))) * 8];
        int r2 = wn * 64 + i * 16 + l15;
        bfr[i] = *(const bf16x8*)&Bs[b * (128 * 64) + (r2 * 8 + (((kk << 2) + lg) ^ (r2 & 7))) * 8];
      }
#pragma unroll
      for (int mi = 0; mi < 4; ++mi)
#pragma unroll
        for (int ni = 0; ni < 4; ++ni)
          acc[mi][ni] = __builtin_amdgcn_mfma_f32_16x16x32_bf16(
              af[mi], bfr[ni], acc[mi][ni], 0, 0, 0);
    }
  };

  issue(0);
  writebuf(0);        // auto vmcnt wait on loads(0)
  issue(64);
  for (int t = 0; t < NK; ++t) {
    asm volatile("s_waitcnt lgkmcnt(0)" ::: "memory");  // own ds_writes done
    __builtin_amdgcn_s_barrier();                       // buf[t&1] visible to all
    __builtin_amdgcn_sched_barrier(0);
    if (t + 1 < NK) writebuf((t + 1) & 1);  // loads(t+1) landed during compute(t-1)
    if (t + 2 < NK) issue((t + 2) * 64);    // in flight across compute(t)
    __builtin_amdgcn_sched_barrier(0);
    compute(t & 1);
  }

  // C/D layout (HW-verified m89): col = lane&15, row = (lane>>4)*4 + reg
  if (n0 < 2 * DMODEL) {                 // Q,K region: bf16 row-major qkv
#pragma unroll
    for (int mi = 0; mi < 4; ++mi)
#pragma unroll
      for (int ni = 0; ni < 4; ++ni) {
        int rb2 = m0 + wm * 64 + mi * 16 + lg * 4;
        int cb = n0 + wn * 64 + ni * 16 + l15;
#pragma unroll
        for (int r = 0; r < 4; ++r)
          C[(size_t)(rb2 + r) * N + cb] = __float2bfloat16(acc[mi][ni][r]);
      }
  } else {                               // V region: vT[e][l] via LDS transpose
    constexpr int TS = 144;              // 128 + 16 pad
    __hip_bfloat16* T = (__hip_bfloat16*)smem;   // [128][144] = 36 KB
    __syncthreads();                     // all waves done with As/Bs
#pragma unroll
    for (int mi = 0; mi < 4; ++mi)
#pragma unroll
      for (int ni = 0; ni < 4; ++ni) {
        int e = wn * 64 + ni * 16 + l15;
        int l = wm * 64 + mi * 16 + lg * 4;
        __align__(8) __hip_bfloat16 o4[4];
#pragma unroll
        for (int r = 0; r < 4; ++r) o4[r] = __float2bfloat16(acc[mi][ni][r]);
        *(uint2*)&T[e * TS + l] = *(const uint2*)o4;
      }
    __syncthreads();
#pragma unroll
    for (int c = tid; c < 128 * 16; c += 256) {        // 16B chunks
      int e = c >> 4, l0 = (c & 15) << 3;
      bf16x8 v = *(const bf16x8*)&T[e * TS + l0];
      *(bf16x8*)&vT[(size_t)(n0 - 2 * DMODEL + e) * L_SEQ + m0 + l0] = v;
    }
  }
}

// ---------------- GEMM2: out[l,e]f32 = attnb[l,d]bf16 * w_fc[e,d]^T f32 ---------
// 64x64 tile, BK=64, 4 waves (wave-tile 32x32). A reg-staged bf16, B fp32->bf16.
__global__ __launch_bounds__(256) void gemm2_rs(
    const __hip_bfloat16* __restrict__ A, const float* __restrict__ B,
    float* __restrict__ C) {
  constexpr int K = 1024, NK = 16, N = DMODEL;
  __shared__ __align__(16) char smem[2 * 64 * 64 * 2 * 2];  // 32 KB
  __hip_bfloat16* As = (__hip_bfloat16*)smem;
  __hip_bfloat16* Bs = (__hip_bfloat16*)(smem + 2 * 64 * 64 * 2);

  const int tid = threadIdx.x, lane = tid & 63, w = tid >> 6;
  const int wm = w >> 1, wn = w & 1, l15 = lane & 15, lg = lane >> 4;
  // XCD swizzle (288 = 8*36), column-chunked
  const int wgid = ((int)blockIdx.x & 7) * 36 + ((int)blockIdx.x >> 3);
  const int n0 = (wgid / 18) * 64, m0 = (wgid % 18) * 64;

  f32x4 acc[2][2] = {};
  int4 ra[2];          // A: 2 chunks x 8 bf16
  float4 rb[2][2];     // B: 2 chunks x 8 f32

  auto issue = [&](int kt) {
#pragma unroll
    for (int i = 0; i < 2; ++i) {
      int c = i * 256 + tid;
      int r = c >> 3, cs = c & 7;
      ra[i] = *(const int4*)(A + (size_t)(m0 + r) * K + kt + cs * 8);
      const float* pb = B + (size_t)(n0 + r) * K + kt + cs * 8;
      rb[i][0] = *(const float4*)pb;
      rb[i][1] = *(const float4*)(pb + 4);
    }
  };
  auto writebuf = [&](int b) {
#pragma unroll
    for (int i = 0; i < 2; ++i) {
      int c = i * 256 + tid;
      int r = c >> 3, cs = c & 7;
      bf16x8 vb;
      vb[0] = f2b(rb[i][0].x); vb[1] = f2b(rb[i][0].y);
      vb[2] = f2b(rb[i][0].z); vb[3] = f2b(rb[i][0].w);
      vb[4] = f2b(rb[i][1].x); vb[5] = f2b(rb[i][1].y);
      vb[6] = f2b(rb[i][1].z); vb[7] = f2b(rb[i][1].w);
      int slot = (r * 8 + (cs ^ (r & 7))) * 8;
      *(int4*)&As[b * (64 * 64) + slot] = ra[i];
      *(bf16x8*)&Bs[b * (64 * 64) + slot] = vb;
    }
  };
  auto compute = [&](int b) {
#pragma unroll
    for (int kk = 0; kk < 2; ++kk) {
      bf16x8 af[2], bfr[2];
#pragma unroll
      for (int i = 0; i < 2; ++i) {
        int r = wm * 32 + i * 16 + l15;
        af[i] = *(const bf16x8*)&As[b * (64 * 64) + (r * 8 + (((kk << 2) + lg) ^ (r & 7))) * 8];
        int r2 = wn * 32 + i * 16 + l15;
        bfr[i] = *(const bf16x8*)&Bs[b * (64 * 64) + (r2 * 8 + (((kk << 2) + lg) ^ (r2 & 7))) * 8];
      }
#pragma unroll
      for (int mi = 0; mi < 2; ++mi)
#pragma unroll
        for (int ni = 0; ni < 2; ++ni)
          acc[mi][ni] = __builtin_amdgcn_mfma_f32_16x16x32_bf16(
              af[mi], bfr[ni], acc[mi][ni], 0, 0, 0);
    }
  };

  issue(0);
  writebuf(0);
  issue(64);
  for (int t = 0; t < NK; ++t) {
    asm volatile("s_waitcnt lgkmcnt(0)" ::: "memory");
    __builtin_amdgcn_s_barrier();
    __builtin_amdgcn_sched_barrier(0);
    if (t + 1 < NK) writebuf((t + 1) & 1);
    if (t + 2 < NK) issue((t + 2) * 64);
    __builtin_amdgcn_sched_barrier(0);
    compute(t & 1);
  }

#pragma unroll
  for (int mi = 0; mi < 2; ++mi)
#pragma unroll
    for (int ni = 0; ni < 2; ++ni) {
      int rb2 = m0 + wm * 32 + mi * 16 + lg * 4;
      int cb = n0 + wn * 32 + ni * 16 + l15;
#pragma unroll
      for (int r = 0; r < 4; ++r)
        C[(size_t)(rb2 + r) * N + cb] = acc[mi][ni][r];
    }
}

// ---------------- MFMA flash attention, kv-split x2, staged + counted vmcnt ----
// flat grid 576 (XCD-swizzled: 2 heads per XCD), 256 threads = 4 waves.
__global__ __launch_bounds__(256) void attn_mfma(
    const __hip_bfloat16* __restrict__ qkvb,   // [1152][3072] (Q,K cols 0..2047)
    const __hip_bfloat16* __restrict__ vT,     // [1024][1152]
    __hip_bfloat16* __restrict__ attnb) {      // [1152][1024]
  const int wgid = ((int)blockIdx.x & 7) * 72 + ((int)blockIdx.x >> 3);
  const int h = wgid / 36;
  const int q0 = (wgid % 36) * 32;
  const int tid = threadIdx.x, lane = tid & 63;
  const int w = tid >> 6, half = w >> 1, wq = w & 1;
  const int l15 = lane & 15, lg = lane >> 4;

  __shared__ __align__(16) __hip_bfloat16 Ks[2][2][64 * 64];   // [half][buf]
  __shared__ __align__(16) __hip_bfloat16 VTs[2][2][64 * 64];
  __shared__ __align__(16) __hip_bfloat16 Ps[2][2][16 * 72];   // [half][wq]

  const int qbase = q0 + wq * 16;

  // Q fragments, pre-scaled by 0.125*log2e (scores feed exp2 directly)
  bf16x8 qf[2];
#pragma unroll
  for (int d2 = 0; d2 < 2; ++d2) {
    bf16x8 qr = *(const bf16x8*)&qkvb[(size_t)(qbase + l15) * TD + h * DHEAD + d2 * 32 + lg * 8];
#pragma unroll
    for (int j = 0; j < 8; ++j) {
      unsigned u = ((unsigned)(unsigned short)qr[j]) << 16;
      float f;
      __builtin_memcpy(&f, &u, 4);
      f *= 0.125f * 1.44269504f;
      qf[d2][j] = f2b(f);
    }
  }

  int limr[4];
#pragma unroll
  for (int r = 0; r < 4; ++r) {
    int q = qbase + lg * 4 + r;
    limr[r] = (q < NPC) ? NPC : (q + 1);
  }

  const int maxlim = (q0 < NPC) ? NPC : (q0 + 32);
  const int ns = (maxlim + 63) >> 6;     // 16..18 steps total
  const int ns0 = (ns + 1) >> 1;         // steps for half0; half1 gets ns-ns0

  auto stage = [&](int b, int kv0) {
    int ht = tid & 127;
#pragma unroll
    for (int it = 0; it < 4; ++it) {
      int s = it * 128 + ht;
      int row = s >> 3, gc = (s & 7) ^ (row & 7);   // XOR-swizzled source
      gld_lds16(&qkvb[(size_t)(kv0 + row) * TD + DMODEL + h * DHEAD + gc * 8],
                &Ks[half][b][s * 8]);
      gld_lds16(&vT[(size_t)(h * DHEAD + row) * L_SEQ + kv0 + gc * 8],
                &VTs[half][b][s * 8]);
    }
  };

  stage(0, (half ? ns0 : 0) << 6);

  float lsum[4] = {0.f, 0.f, 0.f, 0.f};
  f32x4 acc_o[4] = {};

  int buf = 0;
  for (int st = 0; st < ns0; ++st) {
    const int my = half ? (ns0 + st) : st;
    const bool active = my < ns;               // half0 always active
    const int kv0 = my << 6;
    const int mylast = half ? ns : ns0;
    const bool pf = active && (my + 1 < mylast);
    if (pf) stage(buf ^ 1, (my + 1) << 6);     // prefetch stays in flight

    if (pf) s_wait_vmcnt<8>();                 // own stage(t) landed
    else    s_wait_vmcnt<0>();
    __builtin_amdgcn_s_barrier();              // everyone's stage(t) landed
    __builtin_amdgcn_sched_barrier(0);

    if (active) {
      // ---- S2 = (Q*log2e/8) K^T ----
      f32x4 sc[4] = {};
      __builtin_amdgcn_s_setprio(1);
#pragma unroll
      for (int d2 = 0; d2 < 2; ++d2)
#pragma unroll
        for (int jj = 0; jj < 4; ++jj) {
          int row = jj * 16 + l15;
          bf16x8 kf = *(const bf16x8*)&Ks[half][buf]
              [(row * 8 + (((d2 << 2) + lg) ^ (row & 7))) * 8];
          sc[jj] = __builtin_amdgcn_mfma_f32_16x16x32_bf16(qf[d2], kf, sc[jj], 0, 0, 0);
        }
      __builtin_amdgcn_s_setprio(0);

      // ---- no-max softmax; mask only live when kv0 >= NPC (wave-uniform) ----
      float pv[4][4];
#pragma unroll
      for (int jj = 0; jj < 4; ++jj)
#pragma unroll
        for (int r = 0; r < 4; ++r) pv[jj][r] = sc[jj][r];
      if (kv0 >= NPC) {
#pragma unroll
        for (int jj = 0; jj < 4; ++jj) {
          int kv = kv0 + jj * 16 + l15;
#pragma unroll
          for (int r = 0; r < 4; ++r)
            if (kv >= limr[r]) pv[jj][r] = -1e30f;
        }
      }
#pragma unroll
      for (int jj = 0; jj < 4; ++jj)
#pragma unroll
        for (int r = 0; r < 4; ++r) {
          float p = exp2f(pv[jj][r]);   // exp2(-1e30) == 0 for masked
          lsum[r] += p;
          pv[jj][r] = p;
        }

      // ---- P -> LDS bounce (stride 72: conflict-free b128 read) ----
      __hip_bfloat16* Pw = &Ps[half][wq][0];
#pragma unroll
      for (int jj = 0; jj < 4; ++jj)
#pragma unroll
        for (int r = 0; r < 4; ++r)
          Pw[(lg * 4 + r) * 72 + jj * 16 + l15] = __float2bfloat16(pv[jj][r]);
      asm volatile("s_waitcnt lgkmcnt(0)" ::: "memory");
      bf16x8 pa[2];
#pragma unroll
      for (int kh = 0; kh < 2; ++kh)
        pa[kh] = *(const bf16x8*)&Pw[l15 * 72 + kh * 32 + lg * 8];

      // ---- O += P V ----
      __builtin_amdgcn_s_setprio(1);
#pragma unroll
      for (int dd = 0; dd < 4; ++dd)
#pragma unroll
        for (int kh = 0; kh < 2; ++kh) {
          int row = dd * 16 + l15;
          bf16x8 vf = *(const bf16x8*)&VTs[half][buf]
              [(row * 8 + (((kh << 2) + lg) ^ (row & 7))) * 8];
          acc_o[dd] = __builtin_amdgcn_mfma_f32_16x16x32_bf16(pa[kh], vf, acc_o[dd], 0, 0, 0);
        }
      __builtin_amdgcn_s_setprio(0);
    }

    __builtin_amdgcn_sched_barrier(0);
    __builtin_amdgcn_s_barrier();              // all waves done reading buf
    buf ^= 1;
  }

  // ---- reduce lsum across the 16-lane group ----
#pragma unroll
  for (int r = 0; r < 4; ++r) {
    float s = lsum[r];
    s += __shfl_xor(s, 1);
    s += __shfl_xor(s, 2);
    s += __shfl_xor(s, 4);
    s += __shfl_xor(s, 8);
    lsum[r] = s;
  }

  // ---- merge halves: plain sums (no max terms) ----
  float* Osh = (float*)&Ks[0][0][0];     // [32 q][64 d] floats (reuses tile LDS)
  float* Lsh = Osh + 32 * 64;            // [32]
  if (half == 1) {
#pragma unroll
    for (int r = 0; r < 4; ++r) {
      Lsh[wq * 16 + lg * 4 + r] = lsum[r];   // uniform over l15: benign dup write
#pragma unroll
      for (int dd = 0; dd < 4; ++dd)
        Osh[(wq * 16 + lg * 4 + r) * 64 + dd * 16 + l15] = acc_o[dd][r];
    }
  }
  __syncthreads();
  if (half == 0) {
#pragma unroll
    for (int r = 0; r < 4; ++r) {
      float inv = 1.0f / (lsum[r] + Lsh[wq * 16 + lg * 4 + r]);
#pragma unroll
      for (int dd = 0; dd < 4; ++dd) {
        float o = (acc_o[dd][r] +
                   Osh[(wq * 16 + lg * 4 + r) * 64 + dd * 16 + l15]) * inv;
        attnb[(size_t)(qbase + lg * 4 + r) * DMODEL + h * DHEAD + dd * 16 + l15] =
            __float2bfloat16(o);
      }
    }
  }
}

// ---------------- launch ----------------
extern "C" void kernel_launch(void* const* d_in, const int* in_sizes, int n_in,
                              void* d_out, int out_size, void* d_ws, size_t ws_size,
                              hipStream_t stream) {
  const float* x     = (const float*)d_in[0];
  const float* w_qkv = (const float*)d_in[1];
  const float* w_fc  = (const float*)d_in[2];
  float* out = (float*)d_out;

  char* ws = (char*)d_ws;
  __hip_bfloat16* qkvb  = (__hip_bfloat16*)(ws + 0);         // 1152*3072*2 = 7077888
  __hip_bfloat16* vT    = (__hip_bfloat16*)(ws + 7077888);   // 1024*1152*2 = 2359296
  __hip_bfloat16* attnb = (__hip_bfloat16*)(ws + 9437184);   // 1152*1024*2 = 2359296

  // qkv[l,e] = sum_d x[l,d] * w_qkv[e,d]; V part written transposed to vT
  gemm1_rs<<<216, 256, 0, stream>>>(x, w_qkv, qkvb, vT);

  attn_mfma<<<576, 256, 0, stream>>>(qkvb, vT, attnb);

  // out[l,e] = sum_d attn[l,d] * w_fc[e,d]
  gemm2_rs<<<288, 256, 0, stream>>>(attnb, w_fc, out);
}

// Round 9
// 65.686 us; speedup vs baseline: 1.1563x; 1.1563x over previous
//
#include <hip/hip_runtime.h>
#include <hip/hip_bf16.h>

// Fused: cvt(fp32->bf16) ; qkv = x @ w_qkv^T (V emitted transposed) ;
// blockmasked 16-head MFMA flash attention (kv-split x2, no-max exp2 softmax) ;
// out = attn @ w_fc^T.  L=1152, D=1024, NH=16, DH=64, N_PC=1024.
// GEMMs: 3-buffer cyclic LDS pipeline, counted vmcnt. XCD-swizzled grids.

typedef short bf16x8 __attribute__((ext_vector_type(8)));
typedef float f32x4 __attribute__((ext_vector_type(4)));

#define L_SEQ   1152
#define NPC     1024
#define DMODEL  1024
#define TD      3072
#define NHEADS  16
#define DHEAD   64

__device__ __forceinline__ void gld_lds16(const void* g, void* l) {
  __builtin_amdgcn_global_load_lds((const __attribute__((address_space(1))) void*)g,
                                   (__attribute__((address_space(3))) void*)l,
                                   16, 0, 0);
}

template <int N>
__device__ __forceinline__ void s_wait_vmcnt() {
  if constexpr (N == 0)       asm volatile("s_waitcnt vmcnt(0)" ::: "memory");
  else if constexpr (N == 4)  asm volatile("s_waitcnt vmcnt(4)" ::: "memory");
  else if constexpr (N == 6)  asm volatile("s_waitcnt vmcnt(6)" ::: "memory");
  else if constexpr (N == 8)  asm volatile("s_waitcnt vmcnt(8)" ::: "memory");
  else if constexpr (N == 12) asm volatile("s_waitcnt vmcnt(12)" ::: "memory");
  else static_assert(N == 0, "add vmcnt case");
}

__device__ __forceinline__ short f2b(float f) {
  __hip_bfloat16 h = __float2bfloat16(f);
  short s;
  __builtin_memcpy(&s, &h, 2);
  return s;
}

// ---------------- fp32 -> bf16, all three tensors in one launch ----------------
__global__ void cvt_all(const float* __restrict__ x, const float* __restrict__ wq,
                        const float* __restrict__ wf,
                        __hip_bfloat16* __restrict__ xb,
                        __hip_bfloat16* __restrict__ wqb,
                        __hip_bfloat16* __restrict__ wfb) {
  const int NX = 1152 * 1024 / 4, NQ = 3072 * 1024 / 4;
  int i = blockIdx.x * blockDim.x + threadIdx.x;
  const float* s; __hip_bfloat16* d; int j;
  if (i < NX) { s = x; d = xb; j = i; }
  else if (i < NX + NQ) { s = wq; d = wqb; j = i - NX; }
  else { s = wf; d = wfb; j = i - NX - NQ; }
  float4 v = ((const float4*)s)[j];
  __align__(8) __hip_bfloat16 o[4];
  o[0] = __float2bfloat16(v.x);
  o[1] = __float2bfloat16(v.y);
  o[2] = __float2bfloat16(v.z);
  o[3] = __float2bfloat16(v.w);
  *(uint2*)&d[(size_t)j * 4] = *(const uint2*)o;
}

// ---------------- bf16 GEMM: C[M,N] = A[M,K] * B[N,K]^T ----------------
// BM x BN tile, BK=64, 256 threads (4 waves 2x2). 3-buffer cyclic LDS pipeline,
// counted vmcnt (2 stages in flight across barriers). XOR-swizzled staging.
// Flat grid, XCD-swizzled (column-chunked): wgid%MT = m-tile, wgid/MT = n-tile.
// MODE 0: C = float. MODE 1: n<2048 -> bf16 qkv; n>=2048 -> vT[e][l] via LDS
// transpose (coalesced 16B stores).
template <int BM, int BN, int MODE, typename OT>
__global__ __launch_bounds__(256) void gemm_bt(
    const __hip_bfloat16* __restrict__ A,
    const __hip_bfloat16* __restrict__ B,
    OT* __restrict__ C, __hip_bfloat16* __restrict__ vT,
    int M, int N, int K, int MT) {
  constexpr int WMT = BM / 2, WNT = BN / 2;   // wave tile
  constexpr int MI = WMT / 16, NI = WNT / 16;
  constexpr int ACH = BM * 8, BCH = BN * 8;   // 16B chunks per k-tile
  constexpr int S = (ACH + BCH) / 256;        // loads per thread per stage
  __shared__ __align__(16) __hip_bfloat16 As[3][BM * 64];
  __shared__ __align__(16) __hip_bfloat16 Bs[3][BN * 64];

  const int tid = threadIdx.x, lane = tid & 63, w = tid >> 6;
  const int wm = w >> 1, wn = w & 1, l15 = lane & 15, lg = lane >> 4;
  const int chunk = (int)gridDim.x >> 3;      // blocks per XCD (grid % 8 == 0)
  const int wgid = ((int)blockIdx.x & 7) * chunk + ((int)blockIdx.x >> 3);
  const int m0 = (wgid % MT) * BM, n0 = (wgid / MT) * BN;

  f32x4 acc[MI][NI] = {};

  auto stage = [&](int b, int kt) {
    const __hip_bfloat16* Ag = A + (size_t)m0 * K + kt;
    const __hip_bfloat16* Bg = B + (size_t)n0 * K + kt;
#pragma unroll
    for (int c = tid; c < ACH; c += 256) {
      int r = c >> 3, gc = (c & 7) ^ (r & 7);     // XOR-swizzled source
      gld_lds16(Ag + (size_t)r * K + gc * 8, &As[b][c * 8]);
    }
#pragma unroll
    for (int c = tid; c < BCH; c += 256) {
      int r = c >> 3, gc = (c & 7) ^ (r & 7);
      gld_lds16(Bg + (size_t)r * K + gc * 8, &Bs[b][c * 8]);
    }
  };

  const int NK = K >> 6;
  stage(0, 0);
  stage(1, 64);
  stage(2, 128);

  int buf = 0;
  for (int t = 0; t < NK; ++t) {
    if (t < NK - 2)       s_wait_vmcnt<2 * S>();   // own stage(t) landed
    else if (t == NK - 2) s_wait_vmcnt<S>();
    else                  s_wait_vmcnt<0>();
    __builtin_amdgcn_s_barrier();                  // everyone's stage(t) landed
    __builtin_amdgcn_sched_barrier(0);

#pragma unroll
    for (int kk = 0; kk < 2; ++kk) {
      bf16x8 af[MI], bfr[NI];
#pragma unroll
      for (int i = 0; i < MI; ++i) {
        int r = wm * WMT + i * 16 + l15;
        af[i] = *(const bf16x8*)&As[buf][(r * 8 + (((kk << 2) + lg) ^ (r & 7))) * 8];
      }
#pragma unroll
      for (int i = 0; i < NI; ++i) {
        int r = wn * WNT + i * 16 + l15;
        bfr[i] = *(const bf16x8*)&Bs[buf][(r * 8 + (((kk << 2) + lg) ^ (r & 7))) * 8];
      }
#pragma unroll
      for (int mi = 0; mi < MI; ++mi)
#pragma unroll
        for (int ni = 0; ni < NI; ++ni)
          acc[mi][ni] = __builtin_amdgcn_mfma_f32_16x16x32_bf16(
              af[mi], bfr[ni], acc[mi][ni], 0, 0, 0);
    }

    __builtin_amdgcn_sched_barrier(0);
    __builtin_amdgcn_s_barrier();                  // all waves done reading buf
    __builtin_amdgcn_sched_barrier(0);
    if (t + 3 < NK) stage(buf, (t + 3) * 64);      // refill freed buffer
    buf = (buf + 1 == 3) ? 0 : buf + 1;
  }

  // C/D layout (HW-verified m89): col = lane&15, row = (lane>>4)*4 + reg
  if constexpr (MODE == 0) {
#pragma unroll
    for (int mi = 0; mi < MI; ++mi)
#pragma unroll
      for (int ni = 0; ni < NI; ++ni) {
        int rb = m0 + wm * WMT + mi * 16 + lg * 4;
        int cb = n0 + wn * WNT + ni * 16 + l15;
#pragma unroll
        for (int r = 0; r < 4; ++r)
          C[(size_t)(rb + r) * N + cb] = acc[mi][ni][r];
      }
  } else if (n0 < 2 * DMODEL) {          // Q,K region: bf16 row-major qkv
#pragma unroll
    for (int mi = 0; mi < MI; ++mi)
#pragma unroll
      for (int ni = 0; ni < NI; ++ni) {
        int rb = m0 + wm * WMT + mi * 16 + lg * 4;
        int cb = n0 + wn * WNT + ni * 16 + l15;
#pragma unroll
        for (int r = 0; r < 4; ++r)
          C[(size_t)(rb + r) * N + cb] = __float2bfloat16(acc[mi][ni][r]);
      }
  } else {                               // V region: vT[e][l] via LDS transpose
    constexpr int TS = BM + 8;           // padded stride
    __hip_bfloat16* T = &As[0][0];       // [BN][TS] fits in As (3*BM*64 elems)
    static_assert(BN * TS <= 3 * BM * 64, "transpose buffer too big");
    __syncthreads();                     // all waves done with As/Bs
#pragma unroll
    for (int mi = 0; mi < MI; ++mi)
#pragma unroll
      for (int ni = 0; ni < NI; ++ni) {
        int e = wn * WNT + ni * 16 + l15;
        int l = wm * WMT + mi * 16 + lg * 4;
        __align__(8) __hip_bfloat16 o4[4];
#pragma unroll
        for (int r = 0; r < 4; ++r) o4[r] = __float2bfloat16(acc[mi][ni][r]);
        *(uint2*)&T[e * TS + l] = *(const uint2*)o4;
      }
    __syncthreads();
#pragma unroll
    for (int c = tid; c < (BN * BM) / 8; c += 256) {   // 16B chunks
      int e = c / (BM / 8), l0 = (c % (BM / 8)) * 8;
      bf16x8 v = *(const bf16x8*)&T[e * TS + l0];
      *(bf16x8*)&vT[(size_t)(n0 - 2 * DMODEL + e) * L_SEQ + m0 + l0] = v;
    }
  }
}

// ---------------- MFMA flash attention, kv-split x2, no-max exp2 softmax -------
// flat grid 576, XCD-swizzled (2 heads per XCD). 256 threads = 4 waves:
// wave = (half = w>>1, wq = w&1). Staged K/V, double-buffered, drain per step.
__global__ __launch_bounds__(256) void attn_mfma(
    const __hip_bfloat16* __restrict__ qkvb,   // [1152][3072] (Q,K cols 0..2047)
    const __hip_bfloat16* __restrict__ vT,     // [1024][1152]
    __hip_bfloat16* __restrict__ attnb) {      // [1152][1024]
  const int wgid = ((int)blockIdx.x & 7) * 72 + ((int)blockIdx.x >> 3);
  const int h = wgid / 36;
  const int q0 = (wgid % 36) * 32;
  const int tid = threadIdx.x, lane = tid & 63;
  const int w = tid >> 6, half = w >> 1, wq = w & 1;
  const int l15 = lane & 15, lg = lane >> 4;

  __shared__ __align__(16) __hip_bfloat16 Ks[2][2][64 * 64];   // [half][buf]
  __shared__ __align__(16) __hip_bfloat16 VTs[2][2][64 * 64];
  __shared__ __align__(16) __hip_bfloat16 Ps[2][2][16 * 72];   // [half][wq]

  const int qbase = q0 + wq * 16;

  // Q fragments, pre-scaled by 0.125*log2e (scores feed exp2 directly)
  bf16x8 qf[2];
#pragma unroll
  for (int d2 = 0; d2 < 2; ++d2) {
    bf16x8 qr = *(const bf16x8*)&qkvb[(size_t)(qbase + l15) * TD + h * DHEAD + d2 * 32 + lg * 8];
#pragma unroll
    for (int j = 0; j < 8; ++j) {
      unsigned u = ((unsigned)(unsigned short)qr[j]) << 16;
      float f;
      __builtin_memcpy(&f, &u, 4);
      f *= 0.125f * 1.44269504f;
      qf[d2][j] = f2b(f);
    }
  }

  int limr[4];
#pragma unroll
  for (int r = 0; r < 4; ++r) {
    int q = qbase + lg * 4 + r;
    limr[r] = (q < NPC) ? NPC : (q + 1);
  }

  const int maxlim = (q0 < NPC) ? NPC : (q0 + 32);
  const int ns = (maxlim + 63) >> 6;     // 16..18 steps total
  const int ns0 = (ns + 1) >> 1;         // steps for half0; half1 gets ns-ns0

  auto stage = [&](int b, int kv0) {
    int ht = tid & 127;
#pragma unroll
    for (int it = 0; it < 4; ++it) {
      int s = it * 128 + ht;
      int row = s >> 3, gc = (s & 7) ^ (row & 7);   // XOR-swizzled source
      gld_lds16(&qkvb[(size_t)(kv0 + row) * TD + DMODEL + h * DHEAD + gc * 8],
                &Ks[half][b][s * 8]);
      gld_lds16(&vT[(size_t)(h * DHEAD + row) * L_SEQ + kv0 + gc * 8],
                &VTs[half][b][s * 8]);
    }
  };

  stage(0, (half ? ns0 : 0) << 6);
  asm volatile("s_waitcnt vmcnt(0)" ::: "memory");
  __syncthreads();

  float lsum[4] = {0.f, 0.f, 0.f, 0.f};
  f32x4 acc_o[4] = {};

  int buf = 0;
  for (int st = 0; st < ns0; ++st) {
    const int my = half ? (ns0 + st) : st;
    const bool active = my < ns;               // half0 always active
    const int kv0 = my << 6;
    const int mylast = half ? ns : ns0;
    if (active && (my + 1 < mylast)) stage(buf ^ 1, (my + 1) << 6);

    if (active) {
      // ---- S2 = (Q*log2e/8) K^T ----
      f32x4 sc[4] = {};
#pragma unroll
      for (int d2 = 0; d2 < 2; ++d2)
#pragma unroll
        for (int jj = 0; jj < 4; ++jj) {
          int row = jj * 16 + l15;
          bf16x8 kf = *(const bf16x8*)&Ks[half][buf]
              [(row * 8 + (((d2 << 2) + lg) ^ (row & 7))) * 8];
          sc[jj] = __builtin_amdgcn_mfma_f32_16x16x32_bf16(qf[d2], kf, sc[jj], 0, 0, 0);
        }

      // ---- no-max exp2 softmax; mask only live when kv0 >= NPC ----
      float pv[4][4];
#pragma unroll
      for (int jj = 0; jj < 4; ++jj)
#pragma unroll
        for (int r = 0; r < 4; ++r) pv[jj][r] = sc[jj][r];
      if (kv0 >= NPC) {
#pragma unroll
        for (int jj = 0; jj < 4; ++jj) {
          int kv = kv0 + jj * 16 + l15;
#pragma unroll
          for (int r = 0; r < 4; ++r)
            if (kv >= limr[r]) pv[jj][r] = -1e30f;
        }
      }
#pragma unroll
      for (int jj = 0; jj < 4; ++jj)
#pragma unroll
        for (int r = 0; r < 4; ++r) {
          float p = exp2f(pv[jj][r]);   // exp2(-1e30) == 0 for masked
          lsum[r] += p;
          pv[jj][r] = p;
        }

      // ---- P -> LDS bounce (stride 72: conflict-free b128 read) ----
      __hip_bfloat16* Pw = &Ps[half][wq][0];
#pragma unroll
      for (int jj = 0; jj < 4; ++jj)
#pragma unroll
        for (int r = 0; r < 4; ++r)
          Pw[(lg * 4 + r) * 72 + jj * 16 + l15] = __float2bfloat16(pv[jj][r]);
      asm volatile("s_waitcnt lgkmcnt(0)" ::: "memory");
      bf16x8 pa[2];
#pragma unroll
      for (int kh = 0; kh < 2; ++kh)
        pa[kh] = *(const bf16x8*)&Pw[l15 * 72 + kh * 32 + lg * 8];

      // ---- O += P V ----
#pragma unroll
      for (int dd = 0; dd < 4; ++dd)
#pragma unroll
        for (int kh = 0; kh < 2; ++kh) {
          int row = dd * 16 + l15;
          bf16x8 vf = *(const bf16x8*)&VTs[half][buf]
              [(row * 8 + (((kh << 2) + lg) ^ (row & 7))) * 8];
          acc_o[dd] = __builtin_amdgcn_mfma_f32_16x16x32_bf16(pa[kh], vf, acc_o[dd], 0, 0, 0);
        }
    }

    asm volatile("s_waitcnt vmcnt(0)" ::: "memory");
    __syncthreads();
    buf ^= 1;
  }

  // ---- reduce lsum across the 16-lane group ----
#pragma unroll
  for (int r = 0; r < 4; ++r) {
    float s = lsum[r];
    s += __shfl_xor(s, 1);
    s += __shfl_xor(s, 2);
    s += __shfl_xor(s, 4);
    s += __shfl_xor(s, 8);
    lsum[r] = s;
  }

  // ---- merge halves: plain sums (no max terms) ----
  float* Osh = (float*)&Ks[0][0][0];     // [32 q][64 d] floats (reuses tile LDS)
  float* Lsh = Osh + 32 * 64;            // [32]
  if (half == 1) {
#pragma unroll
    for (int r = 0; r < 4; ++r) {
      Lsh[wq * 16 + lg * 4 + r] = lsum[r];   // uniform over l15: benign dup write
#pragma unroll
      for (int dd = 0; dd < 4; ++dd)
        Osh[(wq * 16 + lg * 4 + r) * 64 + dd * 16 + l15] = acc_o[dd][r];
    }
  }
  __syncthreads();
  if (half == 0) {
#pragma unroll
    for (int r = 0; r < 4; ++r) {
      float inv = 1.0f / (lsum[r] + Lsh[wq * 16 + lg * 4 + r]);
#pragma unroll
      for (int dd = 0; dd < 4; ++dd) {
        float o = (acc_o[dd][r] +
                   Osh[(wq * 16 + lg * 4 + r) * 64 + dd * 16 + l15]) * inv;
        attnb[(size_t)(qbase + lg * 4 + r) * DMODEL + h * DHEAD + dd * 16 + l15] =
            __float2bfloat16(o);
      }
    }
  }
}

// ---------------- launch ----------------
extern "C" void kernel_launch(void* const* d_in, const int* in_sizes, int n_in,
                              void* d_out, int out_size, void* d_ws, size_t ws_size,
                              hipStream_t stream) {
  const float* x     = (const float*)d_in[0];
  const float* w_qkv = (const float*)d_in[1];
  const float* w_fc  = (const float*)d_in[2];
  float* out = (float*)d_out;

  char* ws = (char*)d_ws;
  __hip_bfloat16* xb    = (__hip_bfloat16*)(ws + 0);         // 2359296 B
  __hip_bfloat16* wqkvb = (__hip_bfloat16*)(ws + 2359296);   // 6291456 B
  __hip_bfloat16* wfcb  = (__hip_bfloat16*)(ws + 8650752);   // 2097152 B
  __hip_bfloat16* qkvb  = (__hip_bfloat16*)(ws + 10747904);  // 7077888 B (V region unused)
  __hip_bfloat16* vT    = (__hip_bfloat16*)(ws + 17825792);  // 2359296 B
  __hip_bfloat16* attnb = (__hip_bfloat16*)(ws + 20185088);  // 2359296 B

  cvt_all<<<5248, 256, 0, stream>>>(x, w_qkv, w_fc, xb, wqkvb, wfcb);

  // qkv[l,e] = sum_d x[l,d] * w_qkv[e,d]; V part written transposed to vT
  gemm_bt<64, 128, 1, __hip_bfloat16><<<432, 256, 0, stream>>>(
      xb, wqkvb, qkvb, vT, L_SEQ, TD, DMODEL, 18);

  attn_mfma<<<576, 256, 0, stream>>>(qkvb, vT, attnb);

  // out[l,e] = sum_d attn[l,d] * w_fc[e,d]
  gemm_bt<64, 64, 0, float><<<288, 256, 0, stream>>>(
      attnb, wfcb, out, nullptr, L_SEQ, DMODEL, DMODEL, 18);
}